// Round 9
// baseline (1160.521 us; speedup 1.0000x reference)
//
#include <hip/hip_runtime.h>

// ---------------------------------------------------------------------------
// AttentionLayer: B=16 S=12 N=400 D=512 H=8 HD=64
// outputs (flat, fp32): out[16,12,400,512] | scores_hb[128,12,400,400]
//                       | v_hb[128,12,400,64]
// ---------------------------------------------------------------------------

typedef float fvec4 __attribute__((ext_vector_type(4)));
typedef float f32x4 __attribute__((ext_vector_type(4)));
typedef unsigned short usvec4 __attribute__((ext_vector_type(4)));
typedef unsigned short usvec8 __attribute__((ext_vector_type(8)));
typedef short v8s __attribute__((ext_vector_type(8)));

#define DEV __device__ __forceinline__

// RNE f32->bf16 (verified absmax 0.015625; HW v_cvt_pk_bf16_f32 is NOT RNE —
// round-8 regression 7.9e-2. Do not reintroduce.)
DEV unsigned short f2bf(float f) {
  unsigned int u = __builtin_bit_cast(unsigned int, f);
  u += 0x7FFFu + ((u >> 16) & 1u);
  return (unsigned short)(u >> 16);
}

DEV f32x4 mfma16(v8s a, v8s b, f32x4 c) {
  return __builtin_amdgcn_mfma_f32_16x16x32_bf16(a, b, c, 0, 0, 0);
}

DEV void gload16(const void* g, void* l) {
  __builtin_amdgcn_global_load_lds(
      (const __attribute__((address_space(1))) unsigned int*)g,
      (__attribute__((address_space(3))) unsigned int*)l, 16, 0, 0);
}

// all 4 weight matrices (512x512 each) in one launch; blockIdx.y selects
__global__ __launch_bounds__(256) void cvtw_k(const float* __restrict__ w0,
                                              const float* __restrict__ w1,
                                              const float* __restrict__ w2,
                                              const float* __restrict__ w3,
                                              unsigned short* __restrict__ o) {
  const float* w = (blockIdx.y == 0) ? w0 : (blockIdx.y == 1) ? w1
                 : (blockIdx.y == 2) ? w2 : w3;
  unsigned short* op = o + (long)blockIdx.y * 262144;
  long i = ((long)blockIdx.x * 256 + threadIdx.x) * 8;  // grid.x=128 -> exact
  fvec4 a = *reinterpret_cast<const fvec4*>(w + i);
  fvec4 b = *reinterpret_cast<const fvec4*>(w + i + 4);
  usvec8 r;
  r[0] = f2bf(a[0]); r[1] = f2bf(a[1]); r[2] = f2bf(a[2]); r[3] = f2bf(a[3]);
  r[4] = f2bf(b[0]); r[5] = f2bf(b[1]); r[6] = f2bf(b[2]); r[7] = f2bf(b[3]);
  *reinterpret_cast<usvec8*>(op + i) = r;
}

// ---------------------------------------------------------------------------
// Merged projection GEMM (q,k,v in ONE launch; grid 7200 = 8*900 XCD-chunked).
// C[m][n] = sum_k A[m][k]*W[n][k] + bias[n];  M=76800 N=512 K=512, A fp32.
// 128x128x32 tile, 4 waves; B via gload16; A reg-staged (f2bf RNE) + T14
// prefetch (next A loads issued after 2nd barrier, hide under MFMA).
// which 0/1: bf16 -> wq_/wk_ (LDS-coalesced epilogue)
// which 2:   fp32 -> vhb (NT) + bf16 -> wvt transposed [g][hd][node]
// ---------------------------------------------------------------------------
__global__ __launch_bounds__(256) void proj_k(
    const float* __restrict__ qin, const float* __restrict__ kin,
    const float* __restrict__ vin, const unsigned short* __restrict__ wW,
    const float* __restrict__ bqp, const float* __restrict__ bkp,
    const float* __restrict__ bvp, unsigned short* __restrict__ wq_,
    unsigned short* __restrict__ wk_, float* __restrict__ vhb,
    unsigned short* __restrict__ wvt) {
  __shared__ unsigned short sMem[128 * 136];  // C-tile staging; sA/sB overlay
  unsigned short* sA = sMem;                  // [128][32] linear, 8 KB
  unsigned short* sB = sMem + 4096;           // [128][32] linear, 8 KB
  const int t = threadIdx.x;
  const int lane = t & 63, wid = t >> 6;
  const int wm = wid >> 1, wn = wid & 1;
  const int lr = lane & 15, lg = lane >> 4;
  const int bid = blockIdx.x;
  const int orig = (bid & 7) * 900 + (bid >> 3);
  const int which = orig >= 4800 ? 2 : (orig >= 2400 ? 1 : 0);
  const int inner = orig - which * 2400;
  const long m0 = (long)(inner >> 2) * 128;
  const int n0 = (inner & 3) * 128;

  const float* A = which == 0 ? qin : which == 1 ? kin : vin;
  const unsigned short* W = wW + (long)which * 262144;
  const float* bias = which == 0 ? bqp : which == 1 ? bkp : bvp;

  // B staging (gload16): chunk wid covers rows wid*16..+15
  const int srow = wid * 16 + (lane >> 2);
  const int scol = (lane & 3) * 8;
  const unsigned short* bS0 = W + (long)(n0 + srow) * 512 + scol;
  const unsigned short* bS1 = bS0 + 64 * 512;
  unsigned short* lB0 = sB + wid * 512;
  unsigned short* lB1 = sB + (wid + 4) * 512;

  // A staging: rows (t>>3)+32i, 16B fp32 chunk c=t&7
  const int arow = t >> 3;       // 0..31
  const int acol = (t & 7) * 4;  // f32 col within k-tile
  const float* aP32 = A + (m0 + arow) * 512 + acol;
  unsigned short* aL = sA + arow * 32 + acol;

  f32x4 acc[4][4] = {};
  fvec4 aReg[4];
#pragma unroll
  for (int i = 0; i < 4; i++)
    aReg[i] = *reinterpret_cast<const fvec4*>(aP32 + (long)i * 32 * 512);

  for (int k0 = 0; k0 < 512; k0 += 32) {
    __syncthreads();
    gload16(bS0 + k0, lB0);
    gload16(bS1 + k0, lB1);
#pragma unroll
    for (int i = 0; i < 4; i++) {
      usvec4 pk;
      pk[0] = f2bf(aReg[i][0]); pk[1] = f2bf(aReg[i][1]);
      pk[2] = f2bf(aReg[i][2]); pk[3] = f2bf(aReg[i][3]);
      *reinterpret_cast<usvec4*>(aL + i * 1024) = pk;  // ds_write_b64
    }
    __syncthreads();
    if (k0 < 480) {  // T14: prefetch next A tile; latency hides under MFMA
#pragma unroll
      for (int i = 0; i < 4; i++)
        aReg[i] =
            *reinterpret_cast<const fvec4*>(aP32 + (long)i * 32 * 512 + k0 + 32);
    }

    v8s af[4], bf[4];
#pragma unroll
    for (int i = 0; i < 4; i++)
      af[i] = *reinterpret_cast<const v8s*>(&sA[(wm * 64 + i * 16 + lr) * 32 + lg * 8]);
#pragma unroll
    for (int j = 0; j < 4; j++)
      bf[j] = *reinterpret_cast<const v8s*>(&sB[(wn * 64 + j * 16 + lr) * 32 + lg * 8]);
#pragma unroll
    for (int i = 0; i < 4; i++)
#pragma unroll
      for (int j = 0; j < 4; j++) acc[i][j] = mfma16(af[i], bf[j], acc[i][j]);
  }

  if (which <= 1) {
    unsigned short* o_h = which == 0 ? wq_ : wk_;
    // stage C tile (bf16, +bias) in LDS, then coalesced 64B-segment stores
    __syncthreads();
#pragma unroll
    for (int i = 0; i < 4; i++) {
#pragma unroll
      for (int j = 0; j < 4; j++) {
        const int col = wn * 64 + j * 16 + lr;
        const float bv_ = bias[n0 + col];
#pragma unroll
        for (int r = 0; r < 4; r++) {
          const int row = wm * 64 + i * 16 + lg * 4 + r;
          sMem[row * 136 + col] = f2bf(acc[i][j][r] + bv_);
        }
      }
    }
    __syncthreads();
#pragma unroll
    for (int pass = 0; pass < 2; pass++) {
      const int row = (t >> 2) + pass * 64;
      const int c0 = (t & 3) * 8;  // lanes 0..3 cover 64B consecutive
      const unsigned short* src = &sMem[row * 136 + c0];
      unsigned short* dst = &o_h[(m0 + row) * 512 + n0 + c0];
#pragma unroll
      for (int k = 0; k < 4; k++)
        *reinterpret_cast<usvec8*>(dst + k * 32) =
            *reinterpret_cast<const usvec8*>(src + k * 32);
    }
  } else {
#pragma unroll
    for (int i = 0; i < 4; i++) {
#pragma unroll
      for (int j = 0; j < 4; j++) {
        const int gn = n0 + wn * 64 + j * 16 + lr;
        const float bv_ = bias[gn];
        const long gm0 = m0 + wm * 64 + i * 16 + lg * 4;  // 4-aligned
        const int bs_lin = (int)(gm0 / 400);
        const int node0 = (int)(gm0 - (long)bs_lin * 400);
        const int h = gn >> 6, hd = gn & 63;
        float* vp = vhb + ((((long)(h * 192 + bs_lin) * 400 + node0) << 6) + hd);
        const float v0 = acc[i][j][0] + bv_, v1 = acc[i][j][1] + bv_;
        const float v2 = acc[i][j][2] + bv_, v3 = acc[i][j][3] + bv_;
        __builtin_nontemporal_store(v0, vp);
        __builtin_nontemporal_store(v1, vp + 64);
        __builtin_nontemporal_store(v2, vp + 128);
        __builtin_nontemporal_store(v3, vp + 192);
        usvec4 pk;
        pk[0] = f2bf(v0); pk[1] = f2bf(v1); pk[2] = f2bf(v2); pk[3] = f2bf(v3);
        *reinterpret_cast<usvec4*>(
            wvt + (((long)(bs_lin * 8 + h) * 64 + hd) * 400 + node0)) = pk;
      }
    }
  }
}

// ---------------------------------------------------------------------------
// Output GEMM: out[m][n] = sum_k ctx[m][k]*Wo[n][k] + bo[n]; A bf16 gload16.
// 1D grid 2400, XCD-chunked swizzle, n fastest. fp32 NT stores (pure stream).
// ---------------------------------------------------------------------------
__global__ __launch_bounds__(256) void outgemm_k(
    const unsigned short* __restrict__ A, const unsigned short* __restrict__ W,
    const float* __restrict__ bias, float* __restrict__ o_f) {
  __shared__ unsigned short sA[128 * 32];
  __shared__ unsigned short sB[128 * 32];
  const int t = threadIdx.x;
  const int lane = t & 63, wid = t >> 6;
  const int wm = wid >> 1, wn = wid & 1;
  const int lr = lane & 15, lg = lane >> 4;
  const int bid = blockIdx.x;
  const int orig = (bid & 7) * 300 + (bid >> 3);
  const long m0 = (long)(orig >> 2) * 128;
  const int n0 = (orig & 3) * 128;

  const int srow = wid * 16 + (lane >> 2);
  const int scol = (lane & 3) * 8;
  const unsigned short* aS0 = A + (m0 + srow) * 512 + scol;
  const unsigned short* aS1 = aS0 + 64 * 512;
  const unsigned short* bS0 = W + (long)(n0 + srow) * 512 + scol;
  const unsigned short* bS1 = bS0 + 64 * 512;
  unsigned short* lA0 = sA + wid * 512;
  unsigned short* lA1 = sA + (wid + 4) * 512;
  unsigned short* lB0 = sB + wid * 512;
  unsigned short* lB1 = sB + (wid + 4) * 512;

  f32x4 acc[4][4] = {};

  for (int k0 = 0; k0 < 512; k0 += 32) {
    __syncthreads();
    gload16(aS0 + k0, lA0);
    gload16(aS1 + k0, lA1);
    gload16(bS0 + k0, lB0);
    gload16(bS1 + k0, lB1);
    __syncthreads();

    v8s af[4], bf[4];
#pragma unroll
    for (int i = 0; i < 4; i++)
      af[i] = *reinterpret_cast<const v8s*>(&sA[(wm * 64 + i * 16 + lr) * 32 + lg * 8]);
#pragma unroll
    for (int j = 0; j < 4; j++)
      bf[j] = *reinterpret_cast<const v8s*>(&sB[(wn * 64 + j * 16 + lr) * 32 + lg * 8]);
#pragma unroll
    for (int i = 0; i < 4; i++)
#pragma unroll
      for (int j = 0; j < 4; j++) acc[i][j] = mfma16(af[i], bf[j], acc[i][j]);
  }

#pragma unroll
  for (int i = 0; i < 4; i++) {
#pragma unroll
    for (int j = 0; j < 4; j++) {
      const int gn = n0 + wn * 64 + j * 16 + lr;
      const float bv_ = bias[gn];
#pragma unroll
      for (int r = 0; r < 4; r++) {
        const long gm = m0 + wm * 64 + i * 16 + lg * 4 + r;
        __builtin_nontemporal_store(acc[i][j][r] + bv_, &o_f[gm * 512 + gn]);
      }
    }
  }
}

// ---------------------------------------------------------------------------
// Fused attention: per block = one (bs,h) group x 32 q-rows.
// S = QK^T/8 in registers -> NT-write scores (pure 983MB stream) -> softmax
// via shfl+LDS -> P bf16 to LDS -> PV with V B-frags from wvt (L2).
// 1D grid 19968 (= 8*2496), XCD-chunked swizzle, qb fastest (K/V L2 reuse).
// ---------------------------------------------------------------------------
__global__ __launch_bounds__(256) void attn_k(
    const unsigned short* __restrict__ qm, const unsigned short* __restrict__ km,
    const unsigned short* __restrict__ vt, float* __restrict__ sc,
    unsigned short* __restrict__ ctx) {
  __shared__ unsigned short sP[32][424];  // pitch 848B: 16B-aligned, 2-way banks
  __shared__ float redM[2][32], redS[2][32];
  const int t = threadIdx.x;
  const int lane = t & 63, wid = t >> 6;
  const int wq = wid >> 1, wk = wid & 1;
  const int lr = lane & 15, lg = lane >> 4;
  const int bid = blockIdx.x;
  const int orig = (bid & 7) * 2496 + (bid >> 3);
  const int g = orig / 13, qb = orig - g * 13;
  const int bs = g >> 3, h = g & 7;
  const int q0 = qb * 32;
  const long qkb = (long)bs * 204800 + h * 64;

  int qrow = q0 + wq * 16 + lr;
  if (qrow > 399) qrow = 399;
  const v8s aq0 = *reinterpret_cast<const v8s*>(qm + qkb + (long)qrow * 512 + lg * 8);
  const v8s aq1 = *reinterpret_cast<const v8s*>(qm + qkb + (long)qrow * 512 + 32 + lg * 8);

  f32x4 acc[13];
#pragma unroll
  for (int f = 0; f < 13; f++) acc[f] = f32x4{0.f, 0.f, 0.f, 0.f};

#pragma unroll
  for (int f = 0; f < 13; f++) {
    int kr = wk * 208 + f * 16 + lr;
    if (kr > 399) kr = 399;
    const v8s b0 = *reinterpret_cast<const v8s*>(km + qkb + (long)kr * 512 + lg * 8);
    const v8s b1 = *reinterpret_cast<const v8s*>(km + qkb + (long)kr * 512 + 32 + lg * 8);
    acc[f] = mfma16(aq0, b0, acc[f]);
    acc[f] = mfma16(aq1, b1, acc[f]);
  }

  const long sb = ((long)h * 192 + bs) * 160000;
  const int rowb = q0 + wq * 16 + lg * 4;
  const int rloc = wq * 16 + lg * 4;
  float mx[4] = {-3.0e38f, -3.0e38f, -3.0e38f, -3.0e38f};
#pragma unroll
  for (int f = 0; f < 13; f++) {
    const int col = wk * 208 + f * 16 + lr;
#pragma unroll
    for (int r = 0; r < 4; r++) {
      float s = acc[f][r] * 0.125f;
      if (col >= 400) s = -3.0e38f;
      acc[f][r] = s;
      mx[r] = fmaxf(mx[r], s);
      if (col < 400 && rowb + r < 400)
        __builtin_nontemporal_store(s, &sc[sb + (long)(rowb + r) * 400 + col]);
    }
  }
#pragma unroll
  for (int d = 1; d < 16; d <<= 1)
#pragma unroll
    for (int r = 0; r < 4; r++) mx[r] = fmaxf(mx[r], __shfl_xor(mx[r], d));
  if (lr == 0) {
#pragma unroll
    for (int r = 0; r < 4; r++) redM[wk][rloc + r] = mx[r];
  }
  __syncthreads();

  float M[4], sum[4] = {0.f, 0.f, 0.f, 0.f};
#pragma unroll
  for (int r = 0; r < 4; r++) M[r] = fmaxf(redM[0][rloc + r], redM[1][rloc + r]);
#pragma unroll
  for (int f = 0; f < 13; f++) {
#pragma unroll
    for (int r = 0; r < 4; r++) {
      float p = __expf(acc[f][r] - M[r]);
      sum[r] += p;
      sP[rloc + r][wk * 208 + f * 16 + lr] = f2bf(p);
    }
  }
#pragma unroll
  for (int d = 1; d < 16; d <<= 1)
#pragma unroll
    for (int r = 0; r < 4; r++) sum[r] += __shfl_xor(sum[r], d);
  if (lr == 0) {
#pragma unroll
    for (int r = 0; r < 4; r++) redS[wk][rloc + r] = sum[r];
  }
  __syncthreads();

  float inv[4];
#pragma unroll
  for (int r = 0; r < 4; r++) inv[r] = 1.0f / (redS[0][rloc + r] + redS[1][rloc + r]);

  const long vtb = (long)g * 25600;
  f32x4 o0 = {0.f, 0.f, 0.f, 0.f}, o1 = {0.f, 0.f, 0.f, 0.f};
#pragma unroll
  for (int ks = 0; ks < 13; ks++) {
    const v8s pa = *reinterpret_cast<const v8s*>(&sP[wq * 16 + lr][ks * 32 + lg * 8]);
    const v8s bv0 = *reinterpret_cast<const v8s*>(
        vt + vtb + (long)(wk * 32 + lr) * 400 + ks * 32 + lg * 8);
    const v8s bv1 = *reinterpret_cast<const v8s*>(
        vt + vtb + (long)(wk * 32 + 16 + lr) * 400 + ks * 32 + lg * 8);
    o0 = mfma16(pa, bv0, o0);
    o1 = mfma16(pa, bv1, o1);
  }

  const long cb = (long)bs * 400 * 512 + h * 64 + wk * 32;
#pragma unroll
  for (int r = 0; r < 4; r++) {
    const int row = rowb + r;
    if (row < 400) {
      ctx[cb + (long)row * 512 + lr] = f2bf(o0[r] * inv[r]);
      ctx[cb + (long)row * 512 + 16 + lr] = f2bf(o1[r] * inv[r]);
    }
  }
}

// ---------------------------------------------------------------------------

extern "C" void kernel_launch(void* const* d_in, const int* in_sizes, int n_in,
                              void* d_out, int out_size, void* d_ws, size_t ws_size,
                              hipStream_t stream) {
  (void)in_sizes; (void)n_in; (void)out_size; (void)ws_size;

  const float* query = (const float*)d_in[0];
  const float* key   = (const float*)d_in[1];
  const float* value = (const float*)d_in[2];
  const float* Wq = (const float*)d_in[3];
  const float* bq = (const float*)d_in[4];
  const float* Wk = (const float*)d_in[5];
  const float* bk = (const float*)d_in[6];
  const float* Wv = (const float*)d_in[7];
  const float* bv = (const float*)d_in[8];
  const float* Wo = (const float*)d_in[9];
  const float* bo = (const float*)d_in[10];

  float* out = (float*)d_out;       // 39,321,600 f32
  float* sc  = out + 39321600ULL;   // 245,760,000 f32 (scores)
  float* vhb = sc + 245760000ULL;   // 39,321,600 f32

  char* ws = (char*)d_ws;
  unsigned short* wq_  = (unsigned short*)ws;                   // 78.6 MB
  unsigned short* wk_  = (unsigned short*)(ws + 78643200ULL);   // 78.6 MB
  unsigned short* wvt  = (unsigned short*)(ws + 157286400ULL);  // 78.6 MB
  unsigned short* wW   = (unsigned short*)(ws + 235929600ULL);  // 2 MB
  unsigned short* wctx = wq_;  // safe alias: each attn block reads exactly the
                               // Q rectangle it later overwrites (barriers in
                               // between order the cross-wave accesses).

  dim3 blk(256);

  hipLaunchKernelGGL(cvtw_k, dim3(128, 4), blk, 0, stream, Wq, Wk, Wv, Wo, wW);

  hipLaunchKernelGGL(proj_k, dim3(7200), blk, 0, stream, query, key, value, wW,
                     bq, bk, bv, wq_, wk_, vhb, wvt);

  hipLaunchKernelGGL(attn_k, dim3(19968), blk, 0, stream, wq_, wk_, wvt, sc, wctx);

  hipLaunchKernelGGL(outgemm_k, dim3(2400), blk, 0, stream, wctx, wW + 786432,
                     bo, out);
}

// Round 10
// 1075.931 us; speedup vs baseline: 1.0786x; 1.0786x over previous
//
#include <hip/hip_runtime.h>

// ---------------------------------------------------------------------------
// AttentionLayer: B=16 S=12 N=400 D=512 H=8 HD=64
// outputs (flat, fp32): out[16,12,400,512] | scores_hb[128,12,400,400]
//                       | v_hb[128,12,400,64]
// NOTE (r3, r9): __builtin_nontemporal_store on these fragment epilogues is a
// ~2x write-cost regression — per-instruction segments are 64B, not full
// 128B lines; L2 write-merge is load-bearing. Do not reintroduce NT.
// NOTE (r8): HW v_cvt_pk_bf16_f32 is not RNE — absmax 7.9e-2 fail. Use f2bf.
// ---------------------------------------------------------------------------

typedef float fvec4 __attribute__((ext_vector_type(4)));
typedef float f32x4 __attribute__((ext_vector_type(4)));
typedef unsigned short usvec4 __attribute__((ext_vector_type(4)));
typedef unsigned short usvec8 __attribute__((ext_vector_type(8)));
typedef short v8s __attribute__((ext_vector_type(8)));

#define DEV __device__ __forceinline__

DEV unsigned short f2bf(float f) {
  unsigned int u = __builtin_bit_cast(unsigned int, f);
  u += 0x7FFFu + ((u >> 16) & 1u);  // RNE
  return (unsigned short)(u >> 16);
}

DEV f32x4 mfma16(v8s a, v8s b, f32x4 c) {
  return __builtin_amdgcn_mfma_f32_16x16x32_bf16(a, b, c, 0, 0, 0);
}

DEV void gload16(const void* g, void* l) {
  __builtin_amdgcn_global_load_lds(
      (const __attribute__((address_space(1))) unsigned int*)g,
      (__attribute__((address_space(3))) unsigned int*)l, 16, 0, 0);
}

// all 4 weight matrices (512x512 each) in one launch; blockIdx.y selects
__global__ __launch_bounds__(256) void cvtw_k(const float* __restrict__ w0,
                                              const float* __restrict__ w1,
                                              const float* __restrict__ w2,
                                              const float* __restrict__ w3,
                                              unsigned short* __restrict__ o) {
  const float* w = (blockIdx.y == 0) ? w0 : (blockIdx.y == 1) ? w1
                 : (blockIdx.y == 2) ? w2 : w3;
  unsigned short* op = o + (long)blockIdx.y * 262144;
  long i = ((long)blockIdx.x * 256 + threadIdx.x) * 8;  // grid.x=128 -> exact
  fvec4 a = *reinterpret_cast<const fvec4*>(w + i);
  fvec4 b = *reinterpret_cast<const fvec4*>(w + i + 4);
  usvec8 r;
  r[0] = f2bf(a[0]); r[1] = f2bf(a[1]); r[2] = f2bf(a[2]); r[3] = f2bf(a[3]);
  r[4] = f2bf(b[0]); r[5] = f2bf(b[1]); r[6] = f2bf(b[2]); r[7] = f2bf(b[3]);
  *reinterpret_cast<usvec8*>(op + i) = r;
}

// ---------------------------------------------------------------------------
// Merged projection GEMM (q,k,v in ONE launch; grid 7200 = 8*900 XCD-chunked).
// C[m][n] = sum_k A[m][k]*W[n][k] + bias[n];  M=76800 N=512 K=512, A fp32.
// 128x128x32 tile, 4 waves; B via gload16; A reg-staged (f2bf RNE) + T14
// prefetch (next A loads issued after 2nd barrier, hide under MFMA).
// which 0/1: bf16 -> wq_/wk_ (LDS-coalesced epilogue)
// which 2:   fp32 -> vhb scatter + bf16 -> wvt transposed [g][hd][node]
// ---------------------------------------------------------------------------
__global__ __launch_bounds__(256) void proj_k(
    const float* __restrict__ qin, const float* __restrict__ kin,
    const float* __restrict__ vin, const unsigned short* __restrict__ wW,
    const float* __restrict__ bqp, const float* __restrict__ bkp,
    const float* __restrict__ bvp, unsigned short* __restrict__ wq_,
    unsigned short* __restrict__ wk_, float* __restrict__ vhb,
    unsigned short* __restrict__ wvt) {
  __shared__ unsigned short sMem[128 * 136];  // C-tile staging; sA/sB overlay
  unsigned short* sA = sMem;                  // [128][32] linear, 8 KB
  unsigned short* sB = sMem + 4096;           // [128][32] linear, 8 KB
  const int t = threadIdx.x;
  const int lane = t & 63, wid = t >> 6;
  const int wm = wid >> 1, wn = wid & 1;
  const int lr = lane & 15, lg = lane >> 4;
  const int bid = blockIdx.x;
  const int orig = (bid & 7) * 900 + (bid >> 3);
  const int which = orig >= 4800 ? 2 : (orig >= 2400 ? 1 : 0);
  const int inner = orig - which * 2400;
  const long m0 = (long)(inner >> 2) * 128;
  const int n0 = (inner & 3) * 128;

  const float* A = which == 0 ? qin : which == 1 ? kin : vin;
  const unsigned short* W = wW + (long)which * 262144;
  const float* bias = which == 0 ? bqp : which == 1 ? bkp : bvp;

  // B staging (gload16): chunk wid covers rows wid*16..+15
  const int srow = wid * 16 + (lane >> 2);
  const int scol = (lane & 3) * 8;
  const unsigned short* bS0 = W + (long)(n0 + srow) * 512 + scol;
  const unsigned short* bS1 = bS0 + 64 * 512;
  unsigned short* lB0 = sB + wid * 512;
  unsigned short* lB1 = sB + (wid + 4) * 512;

  // A staging: rows (t>>3)+32i, 16B fp32 chunk c=t&7
  const int arow = t >> 3;       // 0..31
  const int acol = (t & 7) * 4;  // f32 col within k-tile
  const float* aP32 = A + (m0 + arow) * 512 + acol;
  unsigned short* aL = sA + arow * 32 + acol;

  f32x4 acc[4][4] = {};
  fvec4 aReg[4];
#pragma unroll
  for (int i = 0; i < 4; i++)
    aReg[i] = *reinterpret_cast<const fvec4*>(aP32 + (long)i * 32 * 512);

  for (int k0 = 0; k0 < 512; k0 += 32) {
    __syncthreads();
    gload16(bS0 + k0, lB0);
    gload16(bS1 + k0, lB1);
#pragma unroll
    for (int i = 0; i < 4; i++) {
      usvec4 pk;
      pk[0] = f2bf(aReg[i][0]); pk[1] = f2bf(aReg[i][1]);
      pk[2] = f2bf(aReg[i][2]); pk[3] = f2bf(aReg[i][3]);
      *reinterpret_cast<usvec4*>(aL + i * 1024) = pk;  // ds_write_b64
    }
    __syncthreads();
    if (k0 < 480) {  // T14: prefetch next A tile; latency hides under MFMA
#pragma unroll
      for (int i = 0; i < 4; i++)
        aReg[i] =
            *reinterpret_cast<const fvec4*>(aP32 + (long)i * 32 * 512 + k0 + 32);
    }

    v8s af[4], bf[4];
#pragma unroll
    for (int i = 0; i < 4; i++)
      af[i] = *reinterpret_cast<const v8s*>(&sA[(wm * 64 + i * 16 + lr) * 32 + lg * 8]);
#pragma unroll
    for (int j = 0; j < 4; j++)
      bf[j] = *reinterpret_cast<const v8s*>(&sB[(wn * 64 + j * 16 + lr) * 32 + lg * 8]);
#pragma unroll
    for (int i = 0; i < 4; i++)
#pragma unroll
      for (int j = 0; j < 4; j++) acc[i][j] = mfma16(af[i], bf[j], acc[i][j]);
  }

  if (which <= 1) {
    unsigned short* o_h = which == 0 ? wq_ : wk_;
    // stage C tile (bf16, +bias) in LDS, then coalesced 64B-segment stores
    __syncthreads();
#pragma unroll
    for (int i = 0; i < 4; i++) {
#pragma unroll
      for (int j = 0; j < 4; j++) {
        const int col = wn * 64 + j * 16 + lr;
        const float bv_ = bias[n0 + col];
#pragma unroll
        for (int r = 0; r < 4; r++) {
          const int row = wm * 64 + i * 16 + lg * 4 + r;
          sMem[row * 136 + col] = f2bf(acc[i][j][r] + bv_);
        }
      }
    }
    __syncthreads();
#pragma unroll
    for (int pass = 0; pass < 2; pass++) {
      const int row = (t >> 2) + pass * 64;
      const int c0 = (t & 3) * 8;  // lanes 0..3 cover 64B consecutive
      const unsigned short* src = &sMem[row * 136 + c0];
      unsigned short* dst = &o_h[(m0 + row) * 512 + n0 + c0];
#pragma unroll
      for (int k = 0; k < 4; k++)
        *reinterpret_cast<usvec8*>(dst + k * 32) =
            *reinterpret_cast<const usvec8*>(src + k * 32);
    }
  } else {
#pragma unroll
    for (int i = 0; i < 4; i++) {
#pragma unroll
      for (int j = 0; j < 4; j++) {
        const int gn = n0 + wn * 64 + j * 16 + lr;
        const float bv_ = bias[gn];
        const long gm0 = m0 + wm * 64 + i * 16 + lg * 4;  // 4-aligned
        const int bs_lin = (int)(gm0 / 400);
        const int node0 = (int)(gm0 - (long)bs_lin * 400);
        const int h = gn >> 6, hd = gn & 63;
        float* vp = vhb + ((((long)(h * 192 + bs_lin) * 400 + node0) << 6) + hd);
        const float v0 = acc[i][j][0] + bv_, v1 = acc[i][j][1] + bv_;
        const float v2 = acc[i][j][2] + bv_, v3 = acc[i][j][3] + bv_;
        vp[0] = v0;
        vp[64] = v1;
        vp[128] = v2;
        vp[192] = v3;
        usvec4 pk;
        pk[0] = f2bf(v0); pk[1] = f2bf(v1); pk[2] = f2bf(v2); pk[3] = f2bf(v3);
        *reinterpret_cast<usvec4*>(
            wvt + (((long)(bs_lin * 8 + h) * 64 + hd) * 400 + node0)) = pk;
      }
    }
  }
}

// ---------------------------------------------------------------------------
// Output GEMM: out[m][n] = sum_k ctx[m][k]*Wo[n][k] + bo[n]; A bf16 gload16.
// 1D grid 2400, XCD-chunked swizzle, n fastest. Plain cached fp32 stores.
// ---------------------------------------------------------------------------
__global__ __launch_bounds__(256) void outgemm_k(
    const unsigned short* __restrict__ A, const unsigned short* __restrict__ W,
    const float* __restrict__ bias, float* __restrict__ o_f) {
  __shared__ unsigned short sA[128 * 32];
  __shared__ unsigned short sB[128 * 32];
  const int t = threadIdx.x;
  const int lane = t & 63, wid = t >> 6;
  const int wm = wid >> 1, wn = wid & 1;
  const int lr = lane & 15, lg = lane >> 4;
  const int bid = blockIdx.x;
  const int orig = (bid & 7) * 300 + (bid >> 3);
  const long m0 = (long)(orig >> 2) * 128;
  const int n0 = (orig & 3) * 128;

  const int srow = wid * 16 + (lane >> 2);
  const int scol = (lane & 3) * 8;
  const unsigned short* aS0 = A + (m0 + srow) * 512 + scol;
  const unsigned short* aS1 = aS0 + 64 * 512;
  const unsigned short* bS0 = W + (long)(n0 + srow) * 512 + scol;
  const unsigned short* bS1 = bS0 + 64 * 512;
  unsigned short* lA0 = sA + wid * 512;
  unsigned short* lA1 = sA + (wid + 4) * 512;
  unsigned short* lB0 = sB + wid * 512;
  unsigned short* lB1 = sB + (wid + 4) * 512;

  f32x4 acc[4][4] = {};

  for (int k0 = 0; k0 < 512; k0 += 32) {
    __syncthreads();
    gload16(aS0 + k0, lA0);
    gload16(aS1 + k0, lA1);
    gload16(bS0 + k0, lB0);
    gload16(bS1 + k0, lB1);
    __syncthreads();

    v8s af[4], bf[4];
#pragma unroll
    for (int i = 0; i < 4; i++)
      af[i] = *reinterpret_cast<const v8s*>(&sA[(wm * 64 + i * 16 + lr) * 32 + lg * 8]);
#pragma unroll
    for (int j = 0; j < 4; j++)
      bf[j] = *reinterpret_cast<const v8s*>(&sB[(wn * 64 + j * 16 + lr) * 32 + lg * 8]);
#pragma unroll
    for (int i = 0; i < 4; i++)
#pragma unroll
      for (int j = 0; j < 4; j++) acc[i][j] = mfma16(af[i], bf[j], acc[i][j]);
  }

#pragma unroll
  for (int i = 0; i < 4; i++) {
#pragma unroll
    for (int j = 0; j < 4; j++) {
      const int gn = n0 + wn * 64 + j * 16 + lr;
      const float bv_ = bias[gn];
#pragma unroll
      for (int r = 0; r < 4; r++) {
        const long gm = m0 + wm * 64 + i * 16 + lg * 4 + r;
        o_f[gm * 512 + gn] = acc[i][j][r] + bv_;
      }
    }
  }
}

// ---------------------------------------------------------------------------
// Fused attention: per block = one (bs,h) group x 32 q-rows.
// S = QK^T/8 in registers -> write scores -> softmax via shfl+LDS
// -> P bf16 to LDS -> PV with V B-frags direct from global wvt (L2).
// 1D grid 19968 (= 8*2496), XCD-chunked swizzle, qb fastest (K/V L2 reuse).
// ---------------------------------------------------------------------------
__global__ __launch_bounds__(256) void attn_k(
    const unsigned short* __restrict__ qm, const unsigned short* __restrict__ km,
    const unsigned short* __restrict__ vt, float* __restrict__ sc,
    unsigned short* __restrict__ ctx) {
  __shared__ unsigned short sP[32][424];  // pitch 848B: 16B-aligned, 2-way banks
  __shared__ float redM[2][32], redS[2][32];
  const int t = threadIdx.x;
  const int lane = t & 63, wid = t >> 6;
  const int wq = wid >> 1, wk = wid & 1;
  const int lr = lane & 15, lg = lane >> 4;
  const int bid = blockIdx.x;
  const int orig = (bid & 7) * 2496 + (bid >> 3);
  const int g = orig / 13, qb = orig - g * 13;
  const int bs = g >> 3, h = g & 7;
  const int q0 = qb * 32;
  const long qkb = (long)bs * 204800 + h * 64;

  int qrow = q0 + wq * 16 + lr;
  if (qrow > 399) qrow = 399;
  const v8s aq0 = *reinterpret_cast<const v8s*>(qm + qkb + (long)qrow * 512 + lg * 8);
  const v8s aq1 = *reinterpret_cast<const v8s*>(qm + qkb + (long)qrow * 512 + 32 + lg * 8);

  f32x4 acc[13];
#pragma unroll
  for (int f = 0; f < 13; f++) acc[f] = f32x4{0.f, 0.f, 0.f, 0.f};

#pragma unroll
  for (int f = 0; f < 13; f++) {
    int kr = wk * 208 + f * 16 + lr;
    if (kr > 399) kr = 399;
    const v8s b0 = *reinterpret_cast<const v8s*>(km + qkb + (long)kr * 512 + lg * 8);
    const v8s b1 = *reinterpret_cast<const v8s*>(km + qkb + (long)kr * 512 + 32 + lg * 8);
    acc[f] = mfma16(aq0, b0, acc[f]);
    acc[f] = mfma16(aq1, b1, acc[f]);
  }

  const long sb = ((long)h * 192 + bs) * 160000;
  const int rowb = q0 + wq * 16 + lg * 4;
  const int rloc = wq * 16 + lg * 4;
  float mx[4] = {-3.0e38f, -3.0e38f, -3.0e38f, -3.0e38f};
#pragma unroll
  for (int f = 0; f < 13; f++) {
    const int col = wk * 208 + f * 16 + lr;
#pragma unroll
    for (int r = 0; r < 4; r++) {
      float s = acc[f][r] * 0.125f;
      if (col >= 400) s = -3.0e38f;
      acc[f][r] = s;
      mx[r] = fmaxf(mx[r], s);
      if (col < 400 && rowb + r < 400)
        sc[sb + (long)(rowb + r) * 400 + col] = s;
    }
  }
#pragma unroll
  for (int d = 1; d < 16; d <<= 1)
#pragma unroll
    for (int r = 0; r < 4; r++) mx[r] = fmaxf(mx[r], __shfl_xor(mx[r], d));
  if (lr == 0) {
#pragma unroll
    for (int r = 0; r < 4; r++) redM[wk][rloc + r] = mx[r];
  }
  __syncthreads();

  float M[4], sum[4] = {0.f, 0.f, 0.f, 0.f};
#pragma unroll
  for (int r = 0; r < 4; r++) M[r] = fmaxf(redM[0][rloc + r], redM[1][rloc + r]);
#pragma unroll
  for (int f = 0; f < 13; f++) {
#pragma unroll
    for (int r = 0; r < 4; r++) {
      float p = __expf(acc[f][r] - M[r]);
      sum[r] += p;
      sP[rloc + r][wk * 208 + f * 16 + lr] = f2bf(p);
    }
  }
#pragma unroll
  for (int d = 1; d < 16; d <<= 1)
#pragma unroll
    for (int r = 0; r < 4; r++) sum[r] += __shfl_xor(sum[r], d);
  if (lr == 0) {
#pragma unroll
    for (int r = 0; r < 4; r++) redS[wk][rloc + r] = sum[r];
  }
  __syncthreads();

  float inv[4];
#pragma unroll
  for (int r = 0; r < 4; r++) inv[r] = 1.0f / (redS[0][rloc + r] + redS[1][rloc + r]);

  const long vtb = (long)g * 25600;
  f32x4 o0 = {0.f, 0.f, 0.f, 0.f}, o1 = {0.f, 0.f, 0.f, 0.f};
#pragma unroll
  for (int ks = 0; ks < 13; ks++) {
    const v8s pa = *reinterpret_cast<const v8s*>(&sP[wq * 16 + lr][ks * 32 + lg * 8]);
    const v8s bv0 = *reinterpret_cast<const v8s*>(
        vt + vtb + (long)(wk * 32 + lr) * 400 + ks * 32 + lg * 8);
    const v8s bv1 = *reinterpret_cast<const v8s*>(
        vt + vtb + (long)(wk * 32 + 16 + lr) * 400 + ks * 32 + lg * 8);
    o0 = mfma16(pa, bv0, o0);
    o1 = mfma16(pa, bv1, o1);
  }

  const long cb = (long)bs * 400 * 512 + h * 64 + wk * 32;
#pragma unroll
  for (int r = 0; r < 4; r++) {
    const int row = rowb + r;
    if (row < 400) {
      ctx[cb + (long)row * 512 + lr] = f2bf(o0[r] * inv[r]);
      ctx[cb + (long)row * 512 + 16 + lr] = f2bf(o1[r] * inv[r]);
    }
  }
}

// ---------------------------------------------------------------------------

extern "C" void kernel_launch(void* const* d_in, const int* in_sizes, int n_in,
                              void* d_out, int out_size, void* d_ws, size_t ws_size,
                              hipStream_t stream) {
  (void)in_sizes; (void)n_in; (void)out_size; (void)ws_size;

  const float* query = (const float*)d_in[0];
  const float* key   = (const float*)d_in[1];
  const float* value = (const float*)d_in[2];
  const float* Wq = (const float*)d_in[3];
  const float* bq = (const float*)d_in[4];
  const float* Wk = (const float*)d_in[5];
  const float* bk = (const float*)d_in[6];
  const float* Wv = (const float*)d_in[7];
  const float* bv = (const float*)d_in[8];
  const float* Wo = (const float*)d_in[9];
  const float* bo = (const float*)d_in[10];

  float* out = (float*)d_out;       // 39,321,600 f32
  float* sc  = out + 39321600ULL;   // 245,760,000 f32 (scores)
  float* vhb = sc + 245760000ULL;   // 39,321,600 f32

  char* ws = (char*)d_ws;
  unsigned short* wq_  = (unsigned short*)ws;                   // 78.6 MB
  unsigned short* wk_  = (unsigned short*)(ws + 78643200ULL);   // 78.6 MB
  unsigned short* wvt  = (unsigned short*)(ws + 157286400ULL);  // 78.6 MB
  unsigned short* wW   = (unsigned short*)(ws + 235929600ULL);  // 2 MB
  unsigned short* wctx = wq_;  // safe alias: each attn block reads exactly the
                               // Q rectangle it later overwrites (barriers in
                               // between order the cross-wave accesses).

  dim3 blk(256);

  hipLaunchKernelGGL(cvtw_k, dim3(128, 4), blk, 0, stream, Wq, Wk, Wv, Wo, wW);

  hipLaunchKernelGGL(proj_k, dim3(7200), blk, 0, stream, query, key, value, wW,
                     bq, bk, bv, wq_, wk_, vhb, wvt);

  hipLaunchKernelGGL(attn_k, dim3(19968), blk, 0, stream, wq_, wk_, wvt, sc, wctx);

  hipLaunchKernelGGL(outgemm_k, dim3(2400), blk, 0, stream, wctx, wW + 786432,
                     bo, out);
}

// Round 11
// 1059.408 us; speedup vs baseline: 1.0954x; 1.0156x over previous
//
#include <hip/hip_runtime.h>

// ---------------------------------------------------------------------------
// AttentionLayer: B=16 S=12 N=400 D=512 H=8 HD=64
// outputs (flat, fp32): out[16,12,400,512] | scores_hb[128,12,400,400]
//                       | v_hb[128,12,400,64]
// NOTE (r3, r9): __builtin_nontemporal_store on these fragment epilogues is a
// ~2x write-cost regression — per-instruction segments are 64B, not full
// 128B lines; L2 write-merge is load-bearing. Do not reintroduce NT.
// NOTE (r8): HW v_cvt_pk_bf16_f32 is not RNE — absmax 7.9e-2 fail. Use f2bf.
// NOTE (r11): GEMM K-loops are 2-phase double-buffered (one barrier/k-step,
// STAGE(next) issued before MFMA(cur)) — at K=512 the old stage->drain->MFMA
// loop exposed full load latency every one of the 16 k-steps.
// ---------------------------------------------------------------------------

typedef float fvec4 __attribute__((ext_vector_type(4)));
typedef float f32x4 __attribute__((ext_vector_type(4)));
typedef unsigned short usvec4 __attribute__((ext_vector_type(4)));
typedef unsigned short usvec8 __attribute__((ext_vector_type(8)));
typedef short v8s __attribute__((ext_vector_type(8)));

#define DEV __device__ __forceinline__

DEV unsigned short f2bf(float f) {
  unsigned int u = __builtin_bit_cast(unsigned int, f);
  u += 0x7FFFu + ((u >> 16) & 1u);  // RNE
  return (unsigned short)(u >> 16);
}

DEV f32x4 mfma16(v8s a, v8s b, f32x4 c) {
  return __builtin_amdgcn_mfma_f32_16x16x32_bf16(a, b, c, 0, 0, 0);
}

DEV void gload16(const void* g, void* l) {
  __builtin_amdgcn_global_load_lds(
      (const __attribute__((address_space(1))) unsigned int*)g,
      (__attribute__((address_space(3))) unsigned int*)l, 16, 0, 0);
}

// all 4 weight matrices (512x512 each) in one launch; blockIdx.y selects
__global__ __launch_bounds__(256) void cvtw_k(const float* __restrict__ w0,
                                              const float* __restrict__ w1,
                                              const float* __restrict__ w2,
                                              const float* __restrict__ w3,
                                              unsigned short* __restrict__ o) {
  const float* w = (blockIdx.y == 0) ? w0 : (blockIdx.y == 1) ? w1
                 : (blockIdx.y == 2) ? w2 : w3;
  unsigned short* op = o + (long)blockIdx.y * 262144;
  long i = ((long)blockIdx.x * 256 + threadIdx.x) * 8;  // grid.x=128 -> exact
  fvec4 a = *reinterpret_cast<const fvec4*>(w + i);
  fvec4 b = *reinterpret_cast<const fvec4*>(w + i + 4);
  usvec8 r;
  r[0] = f2bf(a[0]); r[1] = f2bf(a[1]); r[2] = f2bf(a[2]); r[3] = f2bf(a[3]);
  r[4] = f2bf(b[0]); r[5] = f2bf(b[1]); r[6] = f2bf(b[2]); r[7] = f2bf(b[3]);
  *reinterpret_cast<usvec8*>(op + i) = r;
}

// ---------------------------------------------------------------------------
// Merged projection GEMM (q,k,v in ONE launch; grid 7200 = 8*900 XCD-chunked).
// C[m][n] = sum_k A[m][k]*W[n][k] + bias[n];  M=76800 N=512 K=512, A fp32.
// 128x128x32 tile, 4 waves; 2-phase dbuf: B gload16 + A reg-cvt staged into
// buf^1 BEFORE MFMA on buf[cur]; one barrier per k-step. A regs prefetched
// one iteration ahead so the cvt never waits on HBM.
// LDS: dbuf A 16KB + dbuf B 16KB, overlaid by 34.8KB C-tile after the loop.
// which 0/1: bf16 -> wq_/wk_ (LDS-coalesced epilogue)
// which 2:   fp32 -> vhb scatter + bf16 -> wvt transposed [g][hd][node]
// ---------------------------------------------------------------------------
__global__ __launch_bounds__(256) void proj_k(
    const float* __restrict__ qin, const float* __restrict__ kin,
    const float* __restrict__ vin, const unsigned short* __restrict__ wW,
    const float* __restrict__ bqp, const float* __restrict__ bkp,
    const float* __restrict__ bvp, unsigned short* __restrict__ wq_,
    unsigned short* __restrict__ wk_, float* __restrict__ vhb,
    unsigned short* __restrict__ wvt) {
  // shorts: A bufs [0,4096),[4096,8192); B bufs [8192,12288),[12288,16384)
  // C-tile epilogue overlays [0, 17408)
  __shared__ unsigned short sMem[128 * 136];
  const int t = threadIdx.x;
  const int lane = t & 63, wid = t >> 6;
  const int wm = wid >> 1, wn = wid & 1;
  const int lr = lane & 15, lg = lane >> 4;
  const int bid = blockIdx.x;
  const int orig = (bid & 7) * 900 + (bid >> 3);
  const int which = orig >= 4800 ? 2 : (orig >= 2400 ? 1 : 0);
  const int inner = orig - which * 2400;
  const long m0 = (long)(inner >> 2) * 128;
  const int n0 = (inner & 3) * 128;

  const float* A = which == 0 ? qin : which == 1 ? kin : vin;
  const unsigned short* W = wW + (long)which * 262144;
  const float* bias = which == 0 ? bqp : which == 1 ? bkp : bvp;

  // B staging (gload16): chunk wid covers rows wid*16..+15 (buffer-relative)
  const int srow = wid * 16 + (lane >> 2);
  const int scol = (lane & 3) * 8;
  const unsigned short* bS0 = W + (long)(n0 + srow) * 512 + scol;
  const unsigned short* bS1 = bS0 + 64 * 512;
  const int bOff0 = wid * 512;
  const int bOff1 = (wid + 4) * 512;

  // A staging: rows (t>>3)+32i, 16B fp32 chunk c=t&7 (buffer-relative)
  const int arow = t >> 3;       // 0..31
  const int acol = (t & 7) * 4;  // f32 col within k-tile
  const float* aP32 = A + (m0 + arow) * 512 + acol;
  const int aOff = arow * 32 + acol;

  f32x4 acc[4][4] = {};
  fvec4 aReg[4];
#pragma unroll
  for (int i = 0; i < 4; i++)
    aReg[i] = *reinterpret_cast<const fvec4*>(aP32 + (long)i * 16384);

  {  // prologue: stage tile 0 into buf0, prefetch A regs for tile 1
    unsigned short* sA0 = sMem;
    unsigned short* sB0 = sMem + 8192;
    gload16(bS0, sB0 + bOff0);
    gload16(bS1, sB0 + bOff1);
#pragma unroll
    for (int i = 0; i < 4; i++) {
      usvec4 pk;
      pk[0] = f2bf(aReg[i][0]); pk[1] = f2bf(aReg[i][1]);
      pk[2] = f2bf(aReg[i][2]); pk[3] = f2bf(aReg[i][3]);
      *reinterpret_cast<usvec4*>(sA0 + aOff + i * 1024) = pk;
    }
#pragma unroll
    for (int i = 0; i < 4; i++)
      aReg[i] = *reinterpret_cast<const fvec4*>(aP32 + (long)i * 16384 + 32);
  }
  __syncthreads();

  for (int k0 = 0; k0 < 512; k0 += 32) {
    const int c = (k0 >> 5) & 1;
    unsigned short* sAc = sMem + c * 4096;
    unsigned short* sBc = sMem + 8192 + c * 4096;
    if (k0 < 480) {  // stage tile k0+32 into buf^1 (no barrier until after MFMA)
      unsigned short* sAn = sMem + (c ^ 1) * 4096;
      unsigned short* sBn = sMem + 8192 + (c ^ 1) * 4096;
      gload16(bS0 + k0 + 32, sBn + bOff0);
      gload16(bS1 + k0 + 32, sBn + bOff1);
#pragma unroll
      for (int i = 0; i < 4; i++) {
        usvec4 pk;
        pk[0] = f2bf(aReg[i][0]); pk[1] = f2bf(aReg[i][1]);
        pk[2] = f2bf(aReg[i][2]); pk[3] = f2bf(aReg[i][3]);
        *reinterpret_cast<usvec4*>(sAn + aOff + i * 1024) = pk;
      }
      if (k0 < 448) {
#pragma unroll
        for (int i = 0; i < 4; i++)
          aReg[i] = *reinterpret_cast<const fvec4*>(aP32 + (long)i * 16384 +
                                                    k0 + 64);
      }
    }

    v8s af[4], bf[4];
#pragma unroll
    for (int i = 0; i < 4; i++)
      af[i] = *reinterpret_cast<const v8s*>(&sAc[(wm * 64 + i * 16 + lr) * 32 + lg * 8]);
#pragma unroll
    for (int j = 0; j < 4; j++)
      bf[j] = *reinterpret_cast<const v8s*>(&sBc[(wn * 64 + j * 16 + lr) * 32 + lg * 8]);
#pragma unroll
    for (int i = 0; i < 4; i++)
#pragma unroll
      for (int j = 0; j < 4; j++) acc[i][j] = mfma16(af[i], bf[j], acc[i][j]);
    __syncthreads();
  }

  if (which <= 1) {
    unsigned short* o_h = which == 0 ? wq_ : wk_;
    // stage C tile (bf16, +bias) in LDS, then coalesced 64B-segment stores
#pragma unroll
    for (int i = 0; i < 4; i++) {
#pragma unroll
      for (int j = 0; j < 4; j++) {
        const int col = wn * 64 + j * 16 + lr;
        const float bv_ = bias[n0 + col];
#pragma unroll
        for (int r = 0; r < 4; r++) {
          const int row = wm * 64 + i * 16 + lg * 4 + r;
          sMem[row * 136 + col] = f2bf(acc[i][j][r] + bv_);
        }
      }
    }
    __syncthreads();
#pragma unroll
    for (int pass = 0; pass < 2; pass++) {
      const int row = (t >> 2) + pass * 64;
      const int c0 = (t & 3) * 8;  // lanes 0..3 cover 64B consecutive
      const unsigned short* src = &sMem[row * 136 + c0];
      unsigned short* dst = &o_h[(m0 + row) * 512 + n0 + c0];
#pragma unroll
      for (int k = 0; k < 4; k++)
        *reinterpret_cast<usvec8*>(dst + k * 32) =
            *reinterpret_cast<const usvec8*>(src + k * 32);
    }
  } else {
#pragma unroll
    for (int i = 0; i < 4; i++) {
#pragma unroll
      for (int j = 0; j < 4; j++) {
        const int gn = n0 + wn * 64 + j * 16 + lr;
        const float bv_ = bias[gn];
        const long gm0 = m0 + wm * 64 + i * 16 + lg * 4;  // 4-aligned
        const int bs_lin = (int)(gm0 / 400);
        const int node0 = (int)(gm0 - (long)bs_lin * 400);
        const int h = gn >> 6, hd = gn & 63;
        float* vp = vhb + ((((long)(h * 192 + bs_lin) * 400 + node0) << 6) + hd);
        const float v0 = acc[i][j][0] + bv_, v1 = acc[i][j][1] + bv_;
        const float v2 = acc[i][j][2] + bv_, v3 = acc[i][j][3] + bv_;
        vp[0] = v0;
        vp[64] = v1;
        vp[128] = v2;
        vp[192] = v3;
        usvec4 pk;
        pk[0] = f2bf(v0); pk[1] = f2bf(v1); pk[2] = f2bf(v2); pk[3] = f2bf(v3);
        *reinterpret_cast<usvec4*>(
            wvt + (((long)(bs_lin * 8 + h) * 64 + hd) * 400 + node0)) = pk;
      }
    }
  }
}

// ---------------------------------------------------------------------------
// Output GEMM: out[m][n] = sum_k ctx[m][k]*Wo[n][k] + bo[n]; A,B bf16 gload16.
// 2-phase dbuf, one barrier per k-step. 1D grid 2400, XCD-chunked, n fastest.
// ---------------------------------------------------------------------------
__global__ __launch_bounds__(256) void outgemm_k(
    const unsigned short* __restrict__ A, const unsigned short* __restrict__ W,
    const float* __restrict__ bias, float* __restrict__ o_f) {
  // shorts: A bufs [0,4096),[4096,8192); B bufs [8192,12288),[12288,16384)
  __shared__ unsigned short sMem[16384];
  const int t = threadIdx.x;
  const int lane = t & 63, wid = t >> 6;
  const int wm = wid >> 1, wn = wid & 1;
  const int lr = lane & 15, lg = lane >> 4;
  const int bid = blockIdx.x;
  const int orig = (bid & 7) * 300 + (bid >> 3);
  const long m0 = (long)(orig >> 2) * 128;
  const int n0 = (orig & 3) * 128;

  const int srow = wid * 16 + (lane >> 2);
  const int scol = (lane & 3) * 8;
  const unsigned short* aS0 = A + (m0 + srow) * 512 + scol;
  const unsigned short* aS1 = aS0 + 64 * 512;
  const unsigned short* bS0 = W + (long)(n0 + srow) * 512 + scol;
  const unsigned short* bS1 = bS0 + 64 * 512;
  const int bOff0 = wid * 512;
  const int bOff1 = (wid + 4) * 512;

  f32x4 acc[4][4] = {};

  {  // prologue: stage tile 0 into buf0
    gload16(aS0, sMem + bOff0);
    gload16(aS1, sMem + bOff1);
    gload16(bS0, sMem + 8192 + bOff0);
    gload16(bS1, sMem + 8192 + bOff1);
  }
  __syncthreads();

  for (int k0 = 0; k0 < 512; k0 += 32) {
    const int c = (k0 >> 5) & 1;
    unsigned short* sAc = sMem + c * 4096;
    unsigned short* sBc = sMem + 8192 + c * 4096;
    if (k0 < 480) {
      unsigned short* sAn = sMem + (c ^ 1) * 4096;
      unsigned short* sBn = sMem + 8192 + (c ^ 1) * 4096;
      gload16(aS0 + k0 + 32, sAn + bOff0);
      gload16(aS1 + k0 + 32, sAn + bOff1);
      gload16(bS0 + k0 + 32, sBn + bOff0);
      gload16(bS1 + k0 + 32, sBn + bOff1);
    }

    v8s af[4], bf[4];
#pragma unroll
    for (int i = 0; i < 4; i++)
      af[i] = *reinterpret_cast<const v8s*>(&sAc[(wm * 64 + i * 16 + lr) * 32 + lg * 8]);
#pragma unroll
    for (int j = 0; j < 4; j++)
      bf[j] = *reinterpret_cast<const v8s*>(&sBc[(wn * 64 + j * 16 + lr) * 32 + lg * 8]);
#pragma unroll
    for (int i = 0; i < 4; i++)
#pragma unroll
      for (int j = 0; j < 4; j++) acc[i][j] = mfma16(af[i], bf[j], acc[i][j]);
    __syncthreads();
  }

#pragma unroll
  for (int i = 0; i < 4; i++) {
#pragma unroll
    for (int j = 0; j < 4; j++) {
      const int gn = n0 + wn * 64 + j * 16 + lr;
      const float bv_ = bias[gn];
#pragma unroll
      for (int r = 0; r < 4; r++) {
        const long gm = m0 + wm * 64 + i * 16 + lg * 4 + r;
        o_f[gm * 512 + gn] = acc[i][j][r] + bv_;
      }
    }
  }
}

// ---------------------------------------------------------------------------
// Fused attention: per block = one (bs,h) group x 32 q-rows.
// S = QK^T/8 in registers -> write scores -> softmax via shfl+LDS
// -> P bf16 to LDS -> PV with V B-frags direct from global wvt (L2).
// 1D grid 19968 (= 8*2496), XCD-chunked swizzle, qb fastest (K/V L2 reuse).
// ---------------------------------------------------------------------------
__global__ __launch_bounds__(256) void attn_k(
    const unsigned short* __restrict__ qm, const unsigned short* __restrict__ km,
    const unsigned short* __restrict__ vt, float* __restrict__ sc,
    unsigned short* __restrict__ ctx) {
  __shared__ unsigned short sP[32][424];  // pitch 848B: 16B-aligned, 2-way banks
  __shared__ float redM[2][32], redS[2][32];
  const int t = threadIdx.x;
  const int lane = t & 63, wid = t >> 6;
  const int wq = wid >> 1, wk = wid & 1;
  const int lr = lane & 15, lg = lane >> 4;
  const int bid = blockIdx.x;
  const int orig = (bid & 7) * 2496 + (bid >> 3);
  const int g = orig / 13, qb = orig - g * 13;
  const int bs = g >> 3, h = g & 7;
  const int q0 = qb * 32;
  const long qkb = (long)bs * 204800 + h * 64;

  int qrow = q0 + wq * 16 + lr;
  if (qrow > 399) qrow = 399;
  const v8s aq0 = *reinterpret_cast<const v8s*>(qm + qkb + (long)qrow * 512 + lg * 8);
  const v8s aq1 = *reinterpret_cast<const v8s*>(qm + qkb + (long)qrow * 512 + 32 + lg * 8);

  f32x4 acc[13];
#pragma unroll
  for (int f = 0; f < 13; f++) acc[f] = f32x4{0.f, 0.f, 0.f, 0.f};

#pragma unroll
  for (int f = 0; f < 13; f++) {
    int kr = wk * 208 + f * 16 + lr;
    if (kr > 399) kr = 399;
    const v8s b0 = *reinterpret_cast<const v8s*>(km + qkb + (long)kr * 512 + lg * 8);
    const v8s b1 = *reinterpret_cast<const v8s*>(km + qkb + (long)kr * 512 + 32 + lg * 8);
    acc[f] = mfma16(aq0, b0, acc[f]);
    acc[f] = mfma16(aq1, b1, acc[f]);
  }

  const long sb = ((long)h * 192 + bs) * 160000;
  const int rowb = q0 + wq * 16 + lg * 4;
  const int rloc = wq * 16 + lg * 4;
  float mx[4] = {-3.0e38f, -3.0e38f, -3.0e38f, -3.0e38f};
#pragma unroll
  for (int f = 0; f < 13; f++) {
    const int col = wk * 208 + f * 16 + lr;
#pragma unroll
    for (int r = 0; r < 4; r++) {
      float s = acc[f][r] * 0.125f;
      if (col >= 400) s = -3.0e38f;
      acc[f][r] = s;
      mx[r] = fmaxf(mx[r], s);
      if (col < 400 && rowb + r < 400)
        sc[sb + (long)(rowb + r) * 400 + col] = s;
    }
  }
#pragma unroll
  for (int d = 1; d < 16; d <<= 1)
#pragma unroll
    for (int r = 0; r < 4; r++) mx[r] = fmaxf(mx[r], __shfl_xor(mx[r], d));
  if (lr == 0) {
#pragma unroll
    for (int r = 0; r < 4; r++) redM[wk][rloc + r] = mx[r];
  }
  __syncthreads();

  float M[4], sum[4] = {0.f, 0.f, 0.f, 0.f};
#pragma unroll
  for (int r = 0; r < 4; r++) M[r] = fmaxf(redM[0][rloc + r], redM[1][rloc + r]);
#pragma unroll
  for (int f = 0; f < 13; f++) {
#pragma unroll
    for (int r = 0; r < 4; r++) {
      float p = __expf(acc[f][r] - M[r]);
      sum[r] += p;
      sP[rloc + r][wk * 208 + f * 16 + lr] = f2bf(p);
    }
  }
#pragma unroll
  for (int d = 1; d < 16; d <<= 1)
#pragma unroll
    for (int r = 0; r < 4; r++) sum[r] += __shfl_xor(sum[r], d);
  if (lr == 0) {
#pragma unroll
    for (int r = 0; r < 4; r++) redS[wk][rloc + r] = sum[r];
  }
  __syncthreads();

  float inv[4];
#pragma unroll
  for (int r = 0; r < 4; r++) inv[r] = 1.0f / (redS[0][rloc + r] + redS[1][rloc + r]);

  const long vtb = (long)g * 25600;
  f32x4 o0 = {0.f, 0.f, 0.f, 0.f}, o1 = {0.f, 0.f, 0.f, 0.f};
#pragma unroll
  for (int ks = 0; ks < 13; ks++) {
    const v8s pa = *reinterpret_cast<const v8s*>(&sP[wq * 16 + lr][ks * 32 + lg * 8]);
    const v8s bv0 = *reinterpret_cast<const v8s*>(
        vt + vtb + (long)(wk * 32 + lr) * 400 + ks * 32 + lg * 8);
    const v8s bv1 = *reinterpret_cast<const v8s*>(
        vt + vtb + (long)(wk * 32 + 16 + lr) * 400 + ks * 32 + lg * 8);
    o0 = mfma16(pa, bv0, o0);
    o1 = mfma16(pa, bv1, o1);
  }

  const long cb = (long)bs * 400 * 512 + h * 64 + wk * 32;
#pragma unroll
  for (int r = 0; r < 4; r++) {
    const int row = rowb + r;
    if (row < 400) {
      ctx[cb + (long)row * 512 + lr] = f2bf(o0[r] * inv[r]);
      ctx[cb + (long)row * 512 + 16 + lr] = f2bf(o1[r] * inv[r]);
    }
  }
}

// ---------------------------------------------------------------------------

extern "C" void kernel_launch(void* const* d_in, const int* in_sizes, int n_in,
                              void* d_out, int out_size, void* d_ws, size_t ws_size,
                              hipStream_t stream) {
  (void)in_sizes; (void)n_in; (void)out_size; (void)ws_size;

  const float* query = (const float*)d_in[0];
  const float* key   = (const float*)d_in[1];
  const float* value = (const float*)d_in[2];
  const float* Wq = (const float*)d_in[3];
  const float* bq = (const float*)d_in[4];
  const float* Wk = (const float*)d_in[5];
  const float* bk = (const float*)d_in[6];
  const float* Wv = (const float*)d_in[7];
  const float* bv = (const float*)d_in[8];
  const float* Wo = (const float*)d_in[9];
  const float* bo = (const float*)d_in[10];

  float* out = (float*)d_out;       // 39,321,600 f32
  float* sc  = out + 39321600ULL;   // 245,760,000 f32 (scores)
  float* vhb = sc + 245760000ULL;   // 39,321,600 f32

  char* ws = (char*)d_ws;
  unsigned short* wq_  = (unsigned short*)ws;                   // 78.6 MB
  unsigned short* wk_  = (unsigned short*)(ws + 78643200ULL);   // 78.6 MB
  unsigned short* wvt  = (unsigned short*)(ws + 157286400ULL);  // 78.6 MB
  unsigned short* wW   = (unsigned short*)(ws + 235929600ULL);  // 2 MB
  unsigned short* wctx = wq_;  // safe alias: each attn block reads exactly the
                               // Q rectangle it later overwrites (barriers in
                               // between order the cross-wave accesses).

  dim3 blk(256);

  hipLaunchKernelGGL(cvtw_k, dim3(128, 4), blk, 0, stream, Wq, Wk, Wv, Wo, wW);

  hipLaunchKernelGGL(proj_k, dim3(7200), blk, 0, stream, query, key, value, wW,
                     bq, bk, bv, wq_, wk_, vhb, wvt);

  hipLaunchKernelGGL(attn_k, dim3(19968), blk, 0, stream, wq_, wk_, wvt, sc, wctx);

  hipLaunchKernelGGL(outgemm_k, dim3(2400), blk, 0, stream, wctx, wW + 786432,
                     bo, out);
}